// Round 6
// baseline (205.975 us; speedup 1.0000x reference)
//
#include <hip/hip_runtime.h>

// ProtoSimLoss: fused group-centroid contrastive loss.
// kA(gid+count+scan+CSR) -> kB(centroid) -> kC(dist sums + cfb bf16) ->
// kD(density/percentile -> scale2) ->
// kE(32x32 MFMA GEMM, ring-4 LDS + single-barrier counted-vmcnt pipeline,
//    h-split waves, fused online (M,E,S) loss -> atomic into d_out)

typedef __bf16 v8bf __attribute__((ext_vector_type(8)));
typedef __bf16 v4bf __attribute__((ext_vector_type(4)));
typedef float  v4f  __attribute__((ext_vector_type(4)));
typedef float  v16f __attribute__((ext_vector_type(16)));
typedef unsigned int u32x4 __attribute__((ext_vector_type(4)));

#define B_ROWS 16384
#define ROWS   32768
#define NGRP   1024
#define DIM    512
#define LOG2E  1.4426950408889634f
#define LN2    0.6931471805599453f

__device__ __forceinline__ float wredSum(float v){
#pragma unroll
  for (int o = 32; o > 0; o >>= 1) v += __shfl_xor(v, o);
  return v;
}
__device__ __forceinline__ float wredMax(float v){
#pragma unroll
  for (int o = 32; o > 0; o >>= 1) v = fmaxf(v, __shfl_xor(v, o));
  return v;
}

// async global->LDS 16B DMA (LDS dest = wave-uniform base + lane*16)
__device__ __forceinline__ void gload16(const void* g, void* lds){
  __builtin_amdgcn_global_load_lds(
      (const __attribute__((address_space(1))) void*)g,
      (__attribute__((address_space(3))) void*)lds, 16, 0, 0);
}

// ---- kA: gid, per-group counts, exclusive scan, CSR fill (one block) -------
__global__ __launch_bounds__(1024)
void kA(const int* __restrict__ subj, const int* __restrict__ lab,
        int* __restrict__ base_cnt, int* __restrict__ offs,
        int* __restrict__ gid_arr, int* __restrict__ row_list){
  __shared__ int cnt[NGRP];
  __shared__ int fill[NGRP];
  int t = threadIdx.x;
  cnt[t] = 0;
  __syncthreads();
  int gl[16];
#pragma unroll
  for (int k = 0; k < 16; ++k){
    int i = k * 1024 + t;
    int g = subj[i] * 16 + lab[i];
    gl[k] = g;
    gid_arr[i] = g;
    atomicAdd(&cnt[g], 1);
  }
  __syncthreads();
  int c = cnt[t];
  for (int off = 1; off < NGRP; off <<= 1){
    int v = (t >= off) ? cnt[t - off] : 0;
    __syncthreads();
    cnt[t] += v;
    __syncthreads();
  }
  int ex = cnt[t] - c;
  base_cnt[t] = c;
  offs[t] = ex;
  fill[t] = ex;
  __syncthreads();
#pragma unroll
  for (int k = 0; k < 16; ++k){
    int i = k * 1024 + t;
    int pos = atomicAdd(&fill[gl[k]], 1);
    row_list[pos] = i;
  }
}

// ---- kB: per-group centroid (fp32 + bf16 copies) ------------------------------
__global__ void kB(const float* __restrict__ X, const int* __restrict__ base_cnt,
                   const int* __restrict__ offs, const int* __restrict__ row_list,
                   float* __restrict__ cent_f, __bf16* __restrict__ cent_b){
  int g = blockIdx.x, t = threadIdx.x;              // 1024 blocks x 128 thr
  int n = base_cnt[g], off = offs[g];
  float ax = 0.f, ay = 0.f, az = 0.f, aw = 0.f;
  for (int j = 0; j < n; ++j){
    int r = row_list[off + j];
    const float4* p = (const float4*)(X + (size_t)r * 1024);
    float4 a = p[t];        // v = 0
    float4 b = p[t + 128];  // v = 1
    ax += a.x + b.x; ay += a.y + b.y; az += a.z + b.z; aw += a.w + b.w;
  }
  int cnt2 = 2 * n;
  float inv = 1.0f / (float)(cnt2 > 1 ? cnt2 : 1);
  float4 c; c.x = ax * inv; c.y = ay * inv; c.z = az * inv; c.w = aw * inv;
  ((float4*)(cent_f + (size_t)g * DIM))[t] = c;
  v4bf cb; cb[0] = (__bf16)c.x; cb[1] = (__bf16)c.y; cb[2] = (__bf16)c.z; cb[3] = (__bf16)c.w;
  *(v4bf*)(cent_b + (size_t)g * DIM + t * 4) = cb;
}

// ---- kC: dist -> sqrt(dist) segment sums; write cf bf16 ------------------------
__global__ void kC(const float* __restrict__ X, const int* __restrict__ subj,
                   const int* __restrict__ lab, const float* __restrict__ cent_f,
                   float* __restrict__ msq, __bf16* __restrict__ cfb){
  int w = threadIdx.x >> 6, lane = threadIdx.x & 63;
  int r = blockIdx.x * 4 + w;                       // 8192 blocks x 4 waves
  int i = r & (B_ROWS - 1), v = r >> 14;
  int g = subj[i] * 16 + lab[i];
  const float4* xr = (const float4*)(X + ((size_t)(i * 2 + v)) * DIM);
  const float4* cr = (const float4*)(cent_f + (size_t)g * DIM);
  float4 x0 = xr[lane], x1 = xr[lane + 64];
  float4 c0 = cr[lane], c1 = cr[lane + 64];
  float s = 0.f, d;
  d = x0.x - c0.x; s += d * d;  d = x0.y - c0.y; s += d * d;
  d = x0.z - c0.z; s += d * d;  d = x0.w - c0.w; s += d * d;
  d = x1.x - c1.x; s += d * d;  d = x1.y - c1.y; s += d * d;
  d = x1.z - c1.z; s += d * d;  d = x1.w - c1.w; s += d * d;
  v4bf b0; b0[0]=(__bf16)x0.x; b0[1]=(__bf16)x0.y; b0[2]=(__bf16)x0.z; b0[3]=(__bf16)x0.w;
  v4bf b1; b1[0]=(__bf16)x1.x; b1[1]=(__bf16)x1.y; b1[2]=(__bf16)x1.z; b1[3]=(__bf16)x1.w;
  *(v4bf*)(cfb + (size_t)r * DIM + lane * 4)       = b0;
  *(v4bf*)(cfb + (size_t)r * DIM + 256 + lane * 4) = b1;
  s = wredSum(s);
  if (lane == 0){
    float dist = sqrtf(s);
    atomicAdd(&msq[g], sqrtf(dist));
  }
}

// ---- kD: density, percentile clip, scale2 = log2e/density ---------------------
__global__ void kD(const int* __restrict__ base_cnt, const float* __restrict__ msq,
                   float* __restrict__ scale2){
  __shared__ float sd[NGRP];
  __shared__ float ss[NGRP];
  __shared__ float rb[16];
  int t = threadIdx.x;
  int lane = t & 63, wid = t >> 6;
  int cnt2 = 2 * base_cnt[t];
  float safe = (float)(cnt2 > 1 ? cnt2 : 1);
  float v = (msq[t] / safe) / logf((float)cnt2 + 10.0f);
  float d1 = (cnt2 > 1) ? v : 0.0f;
  float wm = wredMax(d1);
  if (lane == 0) rb[wid] = wm;
  __syncthreads();
  float x = (lane < 16) ? rb[lane] : -3.0e38f;
  if (wid == 0){ x = wredMax(x); if (lane == 0) rb[0] = x; }
  __syncthreads();
  float dmax = rb[0];
  float d2 = (cnt2 > 1) ? d1 : dmax;
  sd[t] = d2;
  __syncthreads();
  int rank = 0;
  for (int j = 0; j < NGRP; ++j){
    float dj = sd[j];
    rank += (dj < d2) || (dj == d2 && j < t);
  }
  ss[rank] = d2;
  __syncthreads();
  float p10 = ss[102] + 0.3f * (ss[103] - ss[102]);
  float p90 = ss[920] + 0.7f * (ss[921] - ss[920]);
  float c = fminf(fmaxf(d2, p10), p90);
  __syncthreads();
  float wsm = wredSum(c);
  if (lane == 0) rb[wid] = wsm;
  __syncthreads();
  float y = (lane < 16) ? rb[lane] : 0.0f;
  if (wid == 0){ y = wredSum(y); if (lane == 0) rb[0] = y; }
  __syncthreads();
  float mean = rb[0] * (1.0f / 1024.0f);
  scale2[t] = LOG2E * mean / (0.1f * c);
}

// ---- kE: sim^T = cent x cf^T via 32x32x16 MFMA, fused online loss -------------
// 512 thr (8 waves): w = h*4 + rw. h = group half (512 groups), rw = row set.
// Each wave owns 32 cf rows in VGPRs (breg[32], K=512); block = 128 rows.
// cent streamed once per block (1 MB) via global_load_lds DMA into a ring-4
// of XOR-swizzled 32 KB tiles [256 trow][8 u32x4]. Single barrier per step:
//   issue stage(t+2) -> vmcnt(8) [own stage(t) landed; barrier makes it
//   all-waves] -> s_barrier -> 16 MFMA on buf[t&3].
// Ring-4 gives 2-step write-after-read separation (proof: any wave past
// barrier(t-1) implies all waves finished MFMA(t-2), the only same-buffer
// reader of stage(t+2)'s destination).
__global__ __launch_bounds__(512, 1)
void kE(const __bf16* __restrict__ cfb, const __bf16* __restrict__ centb,
        const float* __restrict__ scale2, const int* __restrict__ gid_arr,
        float* __restrict__ out){
  __shared__ u32x4 tile[4][2048];     // 128 KB ring-4 (32 KB per stage)
  __shared__ float sscale[NGRP];
  __shared__ float redM[256], redE[256], redS[256];
  int tid = threadIdx.x, lane = tid & 63;
  int w = tid >> 6, rw = w & 3, h = w >> 2;
  int l31 = lane & 31, lhi = lane >> 5;
  int row = blockIdx.x * 128 + rw * 32 + l31;

  if (tid < 256) ((v4f*)sscale)[tid] = ((const v4f*)scale2)[tid];

  // cf row -> registers: 32 u32x4 (this lane's lhi K-interleave)
  u32x4 breg[32];
  {
    const u32x4* rp = (const u32x4*)cfb + (size_t)row * 64 + lhi;
#pragma unroll
    for (int m = 0; m < 32; ++m) breg[m] = rp[2 * m];
  }
  int g0 = gid_arr[row & (B_ROWS - 1)];
  int rsub = g0 >> 4, rlab = g0 & 15;
  // sparse-mask precompute: glab = j + 4*lhi + 8*(q&1) == rlab
  int jm = rlab & 3;
  bool qm1 = (rlab >> 3) & 1;
  bool lhi_ok = ((rlab >> 2) & 1) == lhi;

  const char* gsrc = (const char*)centb;
  auto stage = [&](int t2, int buf){
    int i2 = t2 >> 3, ks2 = t2 & 7;
#pragma unroll
    for (int it = 0; it < 4; ++it){
      int p = it * 512 + tid;
      int trow = p >> 3, clin = p & 7;
      int c = clin ^ (trow & 7);                     // inverse swizzle on src
      int grow = i2 * 128 + (trow & 127) + ((trow >> 7) << 9);
      const void* src = gsrc + ((size_t)(grow * 64 + ks2 * 8 + c) << 4);
      void* dst = (void*)&tile[buf][it * 512 + (w << 6)];
      gload16(src, dst);
    }
  };

  float M = -3.0e38f, E = 0.f, S = 0.f;
  stage(0, 0);
  stage(1, 1);
  // prologue: drain everything once (breg, sscale, stages 0-1)
  asm volatile("s_waitcnt vmcnt(0) lgkmcnt(0)" ::: "memory");
  __builtin_amdgcn_sched_barrier(0);
  __builtin_amdgcn_s_barrier();
  __builtin_amdgcn_sched_barrier(0);

#pragma unroll
  for (int i = 0; i < 4; ++i){
    v16f acc[4];
#pragma unroll
    for (int fm = 0; fm < 4; ++fm)
#pragma unroll
      for (int e = 0; e < 16; ++e) acc[fm][e] = 0.f;

#pragma unroll
    for (int ks = 0; ks < 8; ++ks){
      const int t2 = i * 8 + ks;
      const int buf = t2 & 3;
      // issue 2-ahead, then counted wait (own stage(t2) landed)
      if (t2 <= 29){
        stage(t2 + 2, (t2 + 2) & 3);
        asm volatile("s_waitcnt vmcnt(8)" ::: "memory");
      } else if (t2 == 30){
        asm volatile("s_waitcnt vmcnt(4)" ::: "memory");
      } else {
        asm volatile("s_waitcnt vmcnt(0)" ::: "memory");
      }
      __builtin_amdgcn_sched_barrier(0);
      __builtin_amdgcn_s_barrier();        // all waves' stage(t2) landed
      __builtin_amdgcn_sched_barrier(0);
      // 16 MFMA on buf
#pragma unroll
      for (int kk = 0; kk < 4; ++kk){
#pragma unroll
        for (int fm = 0; fm < 4; ++fm){
          int tr = h * 128 + fm * 32 + l31;
          u32x4 af = tile[buf][tr * 8 + ((kk * 2 + lhi) ^ (tr & 7))];
          acc[fm] = __builtin_amdgcn_mfma_f32_32x32x16_bf16(
              __builtin_bit_cast(v8bf, af),
              __builtin_bit_cast(v8bf, breg[ks * 4 + kk]),
              acc[fm], 0, 0, 0);
        }
      }
    }

    // ---- fold this i-block's 128 groups into running (M,E,S) ----
    // pass 1: scale in place + full max (M is over ALL groups)
    float mloc = -3.0e38f;
#pragma unroll
    for (int fm = 0; fm < 4; ++fm){
      int sbase = h * 512 + i * 128 + fm * 32 + lhi * 4;
#pragma unroll
      for (int q = 0; q < 4; ++q){
        v4f sc = *(const v4f*)&sscale[sbase + q * 8];
#pragma unroll
        for (int j = 0; j < 4; ++j){
          float vv = acc[fm][q * 4 + j] * sc[j];
          acc[fm][q * 4 + j] = vv;
          mloc = fmaxf(mloc, vv);
        }
      }
    }
    float Mn = fmaxf(M, mloc);
    // pass 2: sparse masked E/S — only (j==jm, q&1==qm1, lhi_ok) can match
    float eadd = 0.f, sadd = 0.f;
#pragma unroll
    for (int fm = 0; fm < 4; ++fm){
      float t0 = (jm == 0) ? acc[fm][0]  : (jm == 1) ? acc[fm][1]  : (jm == 2) ? acc[fm][2]  : acc[fm][3];
      float t1 = (jm == 0) ? acc[fm][4]  : (jm == 1) ? acc[fm][5]  : (jm == 2) ? acc[fm][6]  : acc[fm][7];
      float t2s= (jm == 0) ? acc[fm][8]  : (jm == 1) ? acc[fm][9]  : (jm == 2) ? acc[fm][10] : acc[fm][11];
      float t3 = (jm == 0) ? acc[fm][12] : (jm == 1) ? acc[fm][13] : (jm == 2) ? acc[fm][14] : acc[fm][15];
      float u0 = qm1 ? t1 : t0;      // q = qm1      (subject gs+0)
      float u1 = qm1 ? t3 : t2s;     // q = qm1 + 2  (subject gs+1)
      int gs = h * 32 + i * 8 + fm * 2;
      float m0 = (lhi_ok && (gs     != rsub)) ? 1.0f : 0.0f;
      float m1 = (lhi_ok && (gs + 1 != rsub)) ? 1.0f : 0.0f;
      eadd += m0 * exp2f(u0 - Mn) + m1 * exp2f(u1 - Mn);
      sadd += m0 * u0 + m1 * u1;
    }
    E = E * exp2f(M - Mn) + eadd;
    S += sadd;
    M = Mn;
  }

  // lane^32 holds the same cf row's other 16-group-offset half
  {
    float mo = __shfl_xor(M, 32), eo = __shfl_xor(E, 32), so = __shfl_xor(S, 32);
    float mn = fmaxf(M, mo);
    E = E * exp2f(M - mn) + eo * exp2f(mo - mn);
    S += so; M = mn;
  }
  if (lhi == 0){
    redM[w * 32 + l31] = M; redE[w * 32 + l31] = E; redS[w * 32 + l31] = S;
  }
  __syncthreads();
  if (tid < 128){
    float m0 = redM[tid], e0 = redE[tid], s0 = redS[tid];                   // h = 0
    float m1 = redM[tid + 128], e1 = redE[tid + 128], s1 = redS[tid + 128]; // h = 1
    float mn = fmaxf(m0, m1);
    float Ee = e0 * exp2f(m0 - mn) + e1 * exp2f(m1 - mn);
    float Ss = s0 + s1;
    float loss = logf(961.0f + Ee) + LN2 * mn - LN2 * (Ss * (1.0f / 63.0f));
    float ws = wredSum(loss);
    if ((tid & 63) == 0) atomicAdd(out, ws * (1.0f / (float)ROWS));
  }
}

extern "C" void kernel_launch(void* const* d_in, const int* in_sizes, int n_in,
                              void* d_out, int out_size, void* d_ws, size_t ws_size,
                              hipStream_t stream){
  const float* X   = (const float*)d_in[0];
  const int* subj  = (const int*)d_in[1];
  const int* lab   = (const int*)d_in[2];
  char* ws = (char*)d_ws;

  int*    base_cnt = (int*)(ws + 0);          // 4 KB
  float*  msq      = (float*)(ws + 4096);     // 4 KB
  int*    offs     = (int*)(ws + 8192);       // 4 KB
  int*    gid_arr  = (int*)(ws + 12288);      // 64 KB
  int*    row_list = (int*)(ws + 77824);      // 64 KB
  float*  scale2   = (float*)(ws + 143360);   // 4 KB
  float*  cent_f   = (float*)(ws + 147456);   // 2 MB
  __bf16* cent_b   = (__bf16*)(ws + 2244608); // 1 MB
  __bf16* cfb      = (__bf16*)(ws + 3293184); // 32 MB

  hipMemsetAsync(ws, 0, 8192, stream);        // base_cnt, msq
  hipMemsetAsync(d_out, 0, sizeof(float), stream);

  kA <<<1, 1024, 0, stream>>>(subj, lab, base_cnt, offs, gid_arr, row_list);
  kB <<<NGRP, 128, 0, stream>>>(X, base_cnt, offs, row_list, cent_f, cent_b);
  kC <<<8192, 256, 0, stream>>>(X, subj, lab, cent_f, msq, cfb);
  kD <<<1, 1024, 0, stream>>>(base_cnt, msq, scale2);
  kE <<<256, 512, 0, stream>>>(cfb, cent_b, scale2, gid_arr, (float*)d_out);
}

// Round 7
// 154.420 us; speedup vs baseline: 1.3339x; 1.3339x over previous
//
#include <hip/hip_runtime.h>

// ProtoSimLoss: fused group-centroid contrastive loss.
// kA(gid+count+scan+CSR) -> kB(centroid; emits MFMA-fragment-packed centP) ->
// kC(dist sums + cfb bf16) -> kD(density/percentile -> scale2) ->
// kE(barrier-free 32x32x16 MFMA GEMM streaming A-frags from L2/L1,
//    fused online (M,E,S) loss -> atomic into d_out)

typedef __bf16 v8bf __attribute__((ext_vector_type(8)));
typedef __bf16 v4bf __attribute__((ext_vector_type(4)));
typedef float  v4f  __attribute__((ext_vector_type(4)));
typedef float  v16f __attribute__((ext_vector_type(16)));
typedef unsigned int u32x4 __attribute__((ext_vector_type(4)));

#define B_ROWS 16384
#define ROWS   32768
#define NGRP   1024
#define DIM    512
#define LOG2E  1.4426950408889634f
#define LN2    0.6931471805599453f

__device__ __forceinline__ float wredSum(float v){
#pragma unroll
  for (int o = 32; o > 0; o >>= 1) v += __shfl_xor(v, o);
  return v;
}
__device__ __forceinline__ float wredMax(float v){
#pragma unroll
  for (int o = 32; o > 0; o >>= 1) v = fmaxf(v, __shfl_xor(v, o));
  return v;
}

// ---- kA: gid, per-group counts, exclusive scan, CSR fill (one block) -------
__global__ __launch_bounds__(1024)
void kA(const int* __restrict__ subj, const int* __restrict__ lab,
        int* __restrict__ base_cnt, int* __restrict__ offs,
        int* __restrict__ gid_arr, int* __restrict__ row_list){
  __shared__ int cnt[NGRP];
  __shared__ int fill[NGRP];
  int t = threadIdx.x;
  cnt[t] = 0;
  __syncthreads();
  int gl[16];
#pragma unroll
  for (int k = 0; k < 16; ++k){
    int i = k * 1024 + t;
    int g = subj[i] * 16 + lab[i];
    gl[k] = g;
    gid_arr[i] = g;
    atomicAdd(&cnt[g], 1);
  }
  __syncthreads();
  int c = cnt[t];
  for (int off = 1; off < NGRP; off <<= 1){
    int v = (t >= off) ? cnt[t - off] : 0;
    __syncthreads();
    cnt[t] += v;
    __syncthreads();
  }
  int ex = cnt[t] - c;
  base_cnt[t] = c;
  offs[t] = ex;
  fill[t] = ex;
  __syncthreads();
#pragma unroll
  for (int k = 0; k < 16; ++k){
    int i = k * 1024 + t;
    int pos = atomicAdd(&fill[gl[k]], 1);
    row_list[pos] = i;
  }
}

// ---- kB: per-group centroid; fp32 copy + MFMA-fragment-packed bf16 copy ----
// centP layout (bf16): ((gtile*32 + kslice)*64 + half*32 + (g&31))*8 + j
//   gtile=g>>5, d = kslice*16 + half*8 + j   -> kE frag = 1 KB coalesced/wave.
__global__ void kB(const float* __restrict__ X, const int* __restrict__ base_cnt,
                   const int* __restrict__ offs, const int* __restrict__ row_list,
                   float* __restrict__ cent_f, __bf16* __restrict__ centP){
  int g = blockIdx.x, t = threadIdx.x;              // 1024 blocks x 128 thr
  int n = base_cnt[g], off = offs[g];
  float ax = 0.f, ay = 0.f, az = 0.f, aw = 0.f;
  for (int j = 0; j < n; ++j){
    int r = row_list[off + j];
    const float4* p = (const float4*)(X + (size_t)r * 1024);
    float4 a = p[t];        // v = 0
    float4 b = p[t + 128];  // v = 1
    ax += a.x + b.x; ay += a.y + b.y; az += a.z + b.z; aw += a.w + b.w;
  }
  int cnt2 = 2 * n;
  float inv = 1.0f / (float)(cnt2 > 1 ? cnt2 : 1);
  float4 c; c.x = ax * inv; c.y = ay * inv; c.z = az * inv; c.w = aw * inv;
  ((float4*)(cent_f + (size_t)g * DIM))[t] = c;
  // fragment-packed write: d = 4t..4t+3
  int kslice = t >> 2, half = (t >> 1) & 1, j0 = (t & 1) * 4;
  size_t idx = ((size_t)((g >> 5) * 32 + kslice) * 64 + half * 32 + (g & 31)) * 8 + j0;
  v4bf cb; cb[0] = (__bf16)c.x; cb[1] = (__bf16)c.y; cb[2] = (__bf16)c.z; cb[3] = (__bf16)c.w;
  *(v4bf*)(centP + idx) = cb;
}

// ---- kC: dist -> sqrt(dist) segment sums; write cf bf16 ------------------------
__global__ void kC(const float* __restrict__ X, const int* __restrict__ subj,
                   const int* __restrict__ lab, const float* __restrict__ cent_f,
                   float* __restrict__ msq, __bf16* __restrict__ cfb){
  int w = threadIdx.x >> 6, lane = threadIdx.x & 63;
  int r = blockIdx.x * 4 + w;                       // 8192 blocks x 4 waves
  int i = r & (B_ROWS - 1), v = r >> 14;
  int g = subj[i] * 16 + lab[i];
  const float4* xr = (const float4*)(X + ((size_t)(i * 2 + v)) * DIM);
  const float4* cr = (const float4*)(cent_f + (size_t)g * DIM);
  float4 x0 = xr[lane], x1 = xr[lane + 64];
  float4 c0 = cr[lane], c1 = cr[lane + 64];
  float s = 0.f, d;
  d = x0.x - c0.x; s += d * d;  d = x0.y - c0.y; s += d * d;
  d = x0.z - c0.z; s += d * d;  d = x0.w - c0.w; s += d * d;
  d = x1.x - c1.x; s += d * d;  d = x1.y - c1.y; s += d * d;
  d = x1.z - c1.z; s += d * d;  d = x1.w - c1.w; s += d * d;
  v4bf b0; b0[0]=(__bf16)x0.x; b0[1]=(__bf16)x0.y; b0[2]=(__bf16)x0.z; b0[3]=(__bf16)x0.w;
  v4bf b1; b1[0]=(__bf16)x1.x; b1[1]=(__bf16)x1.y; b1[2]=(__bf16)x1.z; b1[3]=(__bf16)x1.w;
  *(v4bf*)(cfb + (size_t)r * DIM + lane * 4)       = b0;
  *(v4bf*)(cfb + (size_t)r * DIM + 256 + lane * 4) = b1;
  s = wredSum(s);
  if (lane == 0){
    float dist = sqrtf(s);
    atomicAdd(&msq[g], sqrtf(dist));
  }
}

// ---- kD: density, percentile clip, scale2 = log2e/density ---------------------
__global__ void kD(const int* __restrict__ base_cnt, const float* __restrict__ msq,
                   float* __restrict__ scale2){
  __shared__ float sd[NGRP];
  __shared__ float ss[NGRP];
  __shared__ float rb[16];
  int t = threadIdx.x;
  int lane = t & 63, wid = t >> 6;
  int cnt2 = 2 * base_cnt[t];
  float safe = (float)(cnt2 > 1 ? cnt2 : 1);
  float v = (msq[t] / safe) / logf((float)cnt2 + 10.0f);
  float d1 = (cnt2 > 1) ? v : 0.0f;
  float wm = wredMax(d1);
  if (lane == 0) rb[wid] = wm;
  __syncthreads();
  float x = (lane < 16) ? rb[lane] : -3.0e38f;
  if (wid == 0){ x = wredMax(x); if (lane == 0) rb[0] = x; }
  __syncthreads();
  float dmax = rb[0];
  float d2 = (cnt2 > 1) ? d1 : dmax;
  sd[t] = d2;
  __syncthreads();
  int rank = 0;
  for (int j = 0; j < NGRP; ++j){
    float dj = sd[j];
    rank += (dj < d2) || (dj == d2 && j < t);
  }
  ss[rank] = d2;
  __syncthreads();
  float p10 = ss[102] + 0.3f * (ss[103] - ss[102]);
  float p90 = ss[920] + 0.7f * (ss[921] - ss[920]);
  float c = fminf(fmaxf(d2, p10), p90);
  __syncthreads();
  float wsm = wredSum(c);
  if (lane == 0) rb[wid] = wsm;
  __syncthreads();
  float y = (lane < 16) ? rb[lane] : 0.0f;
  if (wid == 0){ y = wredSum(y); if (lane == 0) rb[0] = y; }
  __syncthreads();
  float mean = rb[0] * (1.0f / 1024.0f);
  scale2[t] = LOG2E * mean / (0.1f * c);
}

// ---- kE: barrier-free swapped GEMM (sim^T = cent x cf^T), fused loss -----------
// 256 thr / 4 waves: w = h*2 + rw. h = group half (512 groups), rw = row set.
// Wave owns 32 cf rows in VGPRs (breg[32], full K=512) and streams its half of
// centP (512 KB, fragment-packed, sequential) straight from L2/L1 with depth-4
// prefetch. 16 group-tiles x 32 MFMA; per-tile in-register sparse fold.
// No LDS staging, no main-loop barriers. 512 blocks = 2/CU, 2 waves/SIMD.
__global__ __launch_bounds__(256, 1)
void kE(const __bf16* __restrict__ cfb, const u32x4* __restrict__ centP,
        const float* __restrict__ scale2, const int* __restrict__ gid_arr,
        float* __restrict__ out){
  __shared__ float sscale[NGRP];
  __shared__ float redM[128], redE[128], redS[128];
  int tid = threadIdx.x, lane = tid & 63;
  int w = tid >> 6, rw = w & 1, h = w >> 1;
  int l31 = lane & 31, lhi = lane >> 5;
  int row = blockIdx.x * 64 + rw * 32 + l31;

  ((v4f*)sscale)[tid] = ((const v4f*)scale2)[tid];

  // cf row -> registers: 32 u32x4 (this lane's lhi K-interleave)
  u32x4 breg[32];
  {
    const u32x4* rp = (const u32x4*)cfb + (size_t)row * 64 + lhi;
#pragma unroll
    for (int m = 0; m < 32; ++m) breg[m] = rp[2 * m];
  }
  int g0 = gid_arr[row & (B_ROWS - 1)];
  int rsub = g0 >> 4, rlab = g0 & 15;
  int jm = rlab & 3;
  int qm1 = (rlab >> 3) & 1;
  bool lhi_ok = ((rlab >> 2) & 1) == lhi;

  __syncthreads();                       // sscale visible (one-time)

  const u32x4* fp = centP + (size_t)h * 32768 + lane;   // wave's 512 KB stream
  float M = -3.0e38f, E = 0.f, S = 0.f;

  u32x4 f0 = fp[0], f1 = fp[64], f2 = fp[128], f3 = fp[192];

#pragma unroll
  for (int gt = 0; gt < 16; ++gt){
    v16f a0, a1;
#pragma unroll
    for (int e = 0; e < 16; ++e){ a0[e] = 0.f; a1[e] = 0.f; }

#pragma unroll
    for (int k = 0; k < 32; k += 4){
      u32x4 g0v = f0, g1v = f1, g2v = f2, g3v = f3;
      // prefetch 4 ahead; at tile end prefetch next tile's first 4
      // (last tile reads into the 8 KB pad after centP)
      const u32x4* np = fp + ((k < 28) ? (size_t)(k + 4) * 64 : (size_t)2048);
      f0 = np[0]; f1 = np[64]; f2 = np[128]; f3 = np[192];
      a0 = __builtin_amdgcn_mfma_f32_32x32x16_bf16(
          __builtin_bit_cast(v8bf, g0v), __builtin_bit_cast(v8bf, breg[k]),     a0, 0, 0, 0);
      a1 = __builtin_amdgcn_mfma_f32_32x32x16_bf16(
          __builtin_bit_cast(v8bf, g1v), __builtin_bit_cast(v8bf, breg[k + 1]), a1, 0, 0, 0);
      a0 = __builtin_amdgcn_mfma_f32_32x32x16_bf16(
          __builtin_bit_cast(v8bf, g2v), __builtin_bit_cast(v8bf, breg[k + 2]), a0, 0, 0, 0);
      a1 = __builtin_amdgcn_mfma_f32_32x32x16_bf16(
          __builtin_bit_cast(v8bf, g3v), __builtin_bit_cast(v8bf, breg[k + 3]), a1, 0, 0, 0);
    }
    fp += 2048;

    // ---- fold this 32-group tile into running (M,E,S) ----
    // group offset within tile = j + 8*q + 4*lhi (reg = q*4+j);
    // subject = 2*(h*16+gt) + (q>>1); label = offset & 15.
    float mloc = -3.0e38f;
    float u0 = 0.f, u1 = 0.f;
#pragma unroll
    for (int q = 0; q < 4; ++q){
      v4f sc = *(const v4f*)&sscale[(h * 16 + gt) * 32 + q * 8 + lhi * 4];
#pragma unroll
      for (int j = 0; j < 4; ++j){
        float t = (a0[q * 4 + j] + a1[q * 4 + j]) * sc[j];
        mloc = fmaxf(mloc, t);
        if (q < 2) u0 = (q == qm1     && j == jm) ? t : u0;
        else       u1 = (q == qm1 + 2 && j == jm) ? t : u1;
      }
    }
    float Mn = fmaxf(M, mloc);
    int sub0 = 2 * (h * 16 + gt);
    float m0 = (lhi_ok && (sub0     != rsub)) ? 1.0f : 0.0f;
    float m1 = (lhi_ok && (sub0 + 1 != rsub)) ? 1.0f : 0.0f;
    E = E * exp2f(M - Mn) + m0 * exp2f(u0 - Mn) + m1 * exp2f(u1 - Mn);
    S += m0 * u0 + m1 * u1;
    M = Mn;
  }

  // lane^32 holds the same cf row's other group-offset half
  {
    float mo = __shfl_xor(M, 32), eo = __shfl_xor(E, 32), so = __shfl_xor(S, 32);
    float mn = fmaxf(M, mo);
    E = E * exp2f(M - mn) + eo * exp2f(mo - mn);
    S += so; M = mn;
  }
  if (lhi == 0){
    redM[w * 32 + l31] = M; redE[w * 32 + l31] = E; redS[w * 32 + l31] = S;
  }
  __syncthreads();
  if (tid < 64){
    float m0 = redM[tid], e0 = redE[tid], s0 = redS[tid];                   // h = 0
    float m1 = redM[tid + 64], e1 = redE[tid + 64], s1 = redS[tid + 64];    // h = 1
    float mn = fmaxf(m0, m1);
    float Ee = e0 * exp2f(m0 - mn) + e1 * exp2f(m1 - mn);
    float Ss = s0 + s1;
    float loss = logf(961.0f + Ee) + LN2 * mn - LN2 * (Ss * (1.0f / 63.0f));
    float ws = wredSum(loss);
    if (tid == 0) atomicAdd(out, ws * (1.0f / (float)ROWS));
  }
}

extern "C" void kernel_launch(void* const* d_in, const int* in_sizes, int n_in,
                              void* d_out, int out_size, void* d_ws, size_t ws_size,
                              hipStream_t stream){
  const float* X   = (const float*)d_in[0];
  const int* subj  = (const int*)d_in[1];
  const int* lab   = (const int*)d_in[2];
  char* ws = (char*)d_ws;

  int*    base_cnt = (int*)(ws + 0);          // 4 KB
  float*  msq      = (float*)(ws + 4096);     // 4 KB
  int*    offs     = (int*)(ws + 8192);       // 4 KB
  int*    gid_arr  = (int*)(ws + 12288);      // 64 KB
  int*    row_list = (int*)(ws + 77824);      // 64 KB
  float*  scale2   = (float*)(ws + 143360);   // 4 KB
  float*  cent_f   = (float*)(ws + 147456);   // 2 MB  (ends 2244608)
  __bf16* centP    = (__bf16*)(ws + 2244608); // 1 MB + 8 KB pad (ends 3301376)
  __bf16* cfb      = (__bf16*)(ws + 3301376); // 32 MB

  hipMemsetAsync(ws, 0, 8192, stream);        // base_cnt, msq
  hipMemsetAsync(d_out, 0, sizeof(float), stream);

  kA <<<1, 1024, 0, stream>>>(subj, lab, base_cnt, offs, gid_arr, row_list);
  kB <<<NGRP, 128, 0, stream>>>(X, base_cnt, offs, row_list, cent_f, centP);
  kC <<<8192, 256, 0, stream>>>(X, subj, lab, cent_f, msq, cfb);
  kD <<<1, 1024, 0, stream>>>(base_cnt, msq, scale2);
  kE <<<512, 256, 0, stream>>>(cfb, (const u32x4*)centP, scale2, gid_arr, (float*)d_out);
}

// Round 8
// 152.607 us; speedup vs baseline: 1.3497x; 1.0119x over previous
//
#include <hip/hip_runtime.h>

// ProtoSimLoss: fused group-centroid contrastive loss.
// kA(gid+count+scan+CSR) -> kB(centroid; emits MFMA-fragment-packed centP) ->
// kC(dist sums + cfb bf16) -> kD(density/percentile -> scale2) ->
// kE(barrier-free 32x32x16 MFMA GEMM streaming A-frags from L2/L1,
//    breg PINNED in VGPRs, depth-8 prefetch, fused online (M,E,S) loss)

typedef __bf16 v8bf __attribute__((ext_vector_type(8)));
typedef __bf16 v4bf __attribute__((ext_vector_type(4)));
typedef float  v4f  __attribute__((ext_vector_type(4)));
typedef float  v16f __attribute__((ext_vector_type(16)));
typedef unsigned int u32x4 __attribute__((ext_vector_type(4)));

#define B_ROWS 16384
#define ROWS   32768
#define NGRP   1024
#define DIM    512
#define LOG2E  1.4426950408889634f
#define LN2    0.6931471805599453f

__device__ __forceinline__ float wredSum(float v){
#pragma unroll
  for (int o = 32; o > 0; o >>= 1) v += __shfl_xor(v, o);
  return v;
}
__device__ __forceinline__ float wredMax(float v){
#pragma unroll
  for (int o = 32; o > 0; o >>= 1) v = fmaxf(v, __shfl_xor(v, o));
  return v;
}

// ---- kA: gid, per-group counts, exclusive scan, CSR fill (one block) -------
__global__ __launch_bounds__(1024)
void kA(const int* __restrict__ subj, const int* __restrict__ lab,
        int* __restrict__ base_cnt, int* __restrict__ offs,
        int* __restrict__ gid_arr, int* __restrict__ row_list){
  __shared__ int cnt[NGRP];
  __shared__ int fill[NGRP];
  int t = threadIdx.x;
  cnt[t] = 0;
  __syncthreads();
  int gl[16];
#pragma unroll
  for (int k = 0; k < 16; ++k){
    int i = k * 1024 + t;
    int g = subj[i] * 16 + lab[i];
    gl[k] = g;
    gid_arr[i] = g;
    atomicAdd(&cnt[g], 1);
  }
  __syncthreads();
  int c = cnt[t];
  for (int off = 1; off < NGRP; off <<= 1){
    int v = (t >= off) ? cnt[t - off] : 0;
    __syncthreads();
    cnt[t] += v;
    __syncthreads();
  }
  int ex = cnt[t] - c;
  base_cnt[t] = c;
  offs[t] = ex;
  fill[t] = ex;
  __syncthreads();
#pragma unroll
  for (int k = 0; k < 16; ++k){
    int i = k * 1024 + t;
    int pos = atomicAdd(&fill[gl[k]], 1);
    row_list[pos] = i;
  }
}

// ---- kB: per-group centroid; fp32 copy + MFMA-fragment-packed bf16 copy ----
// centP layout (bf16): ((gtile*32 + kslice)*64 + half*32 + (g&31))*8 + j
//   gtile=g>>5, d = kslice*16 + half*8 + j   -> kE frag = 1 KB coalesced/wave.
__global__ void kB(const float* __restrict__ X, const int* __restrict__ base_cnt,
                   const int* __restrict__ offs, const int* __restrict__ row_list,
                   float* __restrict__ cent_f, __bf16* __restrict__ centP){
  int g = blockIdx.x, t = threadIdx.x;              // 1024 blocks x 128 thr
  int n = base_cnt[g], off = offs[g];
  float ax = 0.f, ay = 0.f, az = 0.f, aw = 0.f;
  for (int j = 0; j < n; ++j){
    int r = row_list[off + j];
    const float4* p = (const float4*)(X + (size_t)r * 1024);
    float4 a = p[t];        // v = 0
    float4 b = p[t + 128];  // v = 1
    ax += a.x + b.x; ay += a.y + b.y; az += a.z + b.z; aw += a.w + b.w;
  }
  int cnt2 = 2 * n;
  float inv = 1.0f / (float)(cnt2 > 1 ? cnt2 : 1);
  float4 c; c.x = ax * inv; c.y = ay * inv; c.z = az * inv; c.w = aw * inv;
  ((float4*)(cent_f + (size_t)g * DIM))[t] = c;
  // fragment-packed write: d = 4t..4t+3
  int kslice = t >> 2, half = (t >> 1) & 1, j0 = (t & 1) * 4;
  size_t idx = ((size_t)((g >> 5) * 32 + kslice) * 64 + half * 32 + (g & 31)) * 8 + j0;
  v4bf cb; cb[0] = (__bf16)c.x; cb[1] = (__bf16)c.y; cb[2] = (__bf16)c.z; cb[3] = (__bf16)c.w;
  *(v4bf*)(centP + idx) = cb;
}

// ---- kC: dist -> sqrt(dist) segment sums; write cf bf16 ------------------------
__global__ void kC(const float* __restrict__ X, const int* __restrict__ subj,
                   const int* __restrict__ lab, const float* __restrict__ cent_f,
                   float* __restrict__ msq, __bf16* __restrict__ cfb){
  int w = threadIdx.x >> 6, lane = threadIdx.x & 63;
  int r = blockIdx.x * 4 + w;                       // 8192 blocks x 4 waves
  int i = r & (B_ROWS - 1), v = r >> 14;
  int g = subj[i] * 16 + lab[i];
  const float4* xr = (const float4*)(X + ((size_t)(i * 2 + v)) * DIM);
  const float4* cr = (const float4*)(cent_f + (size_t)g * DIM);
  float4 x0 = xr[lane], x1 = xr[lane + 64];
  float4 c0 = cr[lane], c1 = cr[lane + 64];
  float s = 0.f, d;
  d = x0.x - c0.x; s += d * d;  d = x0.y - c0.y; s += d * d;
  d = x0.z - c0.z; s += d * d;  d = x0.w - c0.w; s += d * d;
  d = x1.x - c1.x; s += d * d;  d = x1.y - c1.y; s += d * d;
  d = x1.z - c1.z; s += d * d;  d = x1.w - c1.w; s += d * d;
  v4bf b0; b0[0]=(__bf16)x0.x; b0[1]=(__bf16)x0.y; b0[2]=(__bf16)x0.z; b0[3]=(__bf16)x0.w;
  v4bf b1; b1[0]=(__bf16)x1.x; b1[1]=(__bf16)x1.y; b1[2]=(__bf16)x1.z; b1[3]=(__bf16)x1.w;
  *(v4bf*)(cfb + (size_t)r * DIM + lane * 4)       = b0;
  *(v4bf*)(cfb + (size_t)r * DIM + 256 + lane * 4) = b1;
  s = wredSum(s);
  if (lane == 0){
    float dist = sqrtf(s);
    atomicAdd(&msq[g], sqrtf(dist));
  }
}

// ---- kD: density, percentile clip, scale2 = log2e/density ---------------------
__global__ void kD(const int* __restrict__ base_cnt, const float* __restrict__ msq,
                   float* __restrict__ scale2){
  __shared__ float sd[NGRP];
  __shared__ float ss[NGRP];
  __shared__ float rb[16];
  int t = threadIdx.x;
  int lane = t & 63, wid = t >> 6;
  int cnt2 = 2 * base_cnt[t];
  float safe = (float)(cnt2 > 1 ? cnt2 : 1);
  float v = (msq[t] / safe) / logf((float)cnt2 + 10.0f);
  float d1 = (cnt2 > 1) ? v : 0.0f;
  float wm = wredMax(d1);
  if (lane == 0) rb[wid] = wm;
  __syncthreads();
  float x = (lane < 16) ? rb[lane] : -3.0e38f;
  if (wid == 0){ x = wredMax(x); if (lane == 0) rb[0] = x; }
  __syncthreads();
  float dmax = rb[0];
  float d2 = (cnt2 > 1) ? d1 : dmax;
  sd[t] = d2;
  __syncthreads();
  int rank = 0;
  for (int j = 0; j < NGRP; ++j){
    float dj = sd[j];
    rank += (dj < d2) || (dj == d2 && j < t);
  }
  ss[rank] = d2;
  __syncthreads();
  float p10 = ss[102] + 0.3f * (ss[103] - ss[102]);
  float p90 = ss[920] + 0.7f * (ss[921] - ss[920]);
  float c = fminf(fmaxf(d2, p10), p90);
  __syncthreads();
  float wsm = wredSum(c);
  if (lane == 0) rb[wid] = wsm;
  __syncthreads();
  float y = (lane < 16) ? rb[lane] : 0.0f;
  if (wid == 0){ y = wredSum(y); if (lane == 0) rb[0] = y; }
  __syncthreads();
  float mean = rb[0] * (1.0f / 1024.0f);
  scale2[t] = LOG2E * mean / (0.1f * c);
}

// ---- kE: barrier-free swapped GEMM (sim^T = cent x cf^T), fused loss -----------
// 256 thr / 4 waves: w = h*2 + rw. h = group half (512 groups), rw = row set.
// Wave owns 32 cf rows PINNED in VGPRs (breg[32], asm-opaque so the compiler
// cannot rematerialize the loads) and streams its half of centP (512 KB,
// fragment-packed, sequential) from L2/L1 with a depth-8 rolling prefetch
// (f0..f7). 16 group-tiles x 32 MFMA; per-tile in-register sparse fold.
// No LDS staging, no main-loop barriers. 512 blocks = 2/CU, 2 waves/SIMD.
__global__ __launch_bounds__(256, 2)
void kE(const __bf16* __restrict__ cfb, const u32x4* __restrict__ centP,
        const float* __restrict__ scale2, const int* __restrict__ gid_arr,
        float* __restrict__ out){
  __shared__ float sscale[NGRP];
  __shared__ float redM[128], redE[128], redS[128];
  int tid = threadIdx.x, lane = tid & 63;
  int w = tid >> 6, rw = w & 1, h = w >> 1;
  int l31 = lane & 31, lhi = lane >> 5;
  int row = blockIdx.x * 64 + rw * 32 + l31;

  ((v4f*)sscale)[tid] = ((const v4f*)scale2)[tid];

  // cf row -> registers: 32 u32x4 (this lane's lhi K-interleave), then PIN
  u32x4 breg[32];
  {
    const u32x4* rp = (const u32x4*)cfb + (size_t)row * 64 + lhi;
#pragma unroll
    for (int m = 0; m < 32; ++m) breg[m] = rp[2 * m];
#pragma unroll
    for (int m = 0; m < 32; ++m) asm volatile("" : "+v"(breg[m]));
  }
  int g0 = gid_arr[row & (B_ROWS - 1)];
  int rsub = g0 >> 4, rlab = g0 & 15;
  int jm = rlab & 3;
  int qm1 = (rlab >> 3) & 1;
  bool lhi_ok = ((rlab >> 2) & 1) == lhi;

  __syncthreads();                       // sscale visible (one-time)

  const u32x4* fp = centP + (size_t)h * 32768 + lane;   // wave's 512 KB stream
  float M = -3.0e38f, E = 0.f, S = 0.f;

  u32x4 f0 = fp[0],   f1 = fp[64],  f2 = fp[128], f3 = fp[192];
  u32x4 f4 = fp[256], f5 = fp[320], f6 = fp[384], f7 = fp[448];

#pragma unroll
  for (int gt = 0; gt < 16; ++gt){
    v16f a0, a1;
#pragma unroll
    for (int e = 0; e < 16; ++e){ a0[e] = 0.f; a1[e] = 0.f; }

#pragma unroll
    for (int k = 0; k < 32; k += 8){
      // next 8 fragments: contiguous across tiles (next tile = fp + 2048);
      // last tile's lookahead lands in the 8 KB pad after centP.
      const u32x4* np = fp + (size_t)(k + 8) * 64;
      a0 = __builtin_amdgcn_mfma_f32_32x32x16_bf16(
          __builtin_bit_cast(v8bf, f0), __builtin_bit_cast(v8bf, breg[k + 0]), a0, 0, 0, 0);
      f0 = np[0];
      a1 = __builtin_amdgcn_mfma_f32_32x32x16_bf16(
          __builtin_bit_cast(v8bf, f1), __builtin_bit_cast(v8bf, breg[k + 1]), a1, 0, 0, 0);
      f1 = np[64];
      a0 = __builtin_amdgcn_mfma_f32_32x32x16_bf16(
          __builtin_bit_cast(v8bf, f2), __builtin_bit_cast(v8bf, breg[k + 2]), a0, 0, 0, 0);
      f2 = np[128];
      a1 = __builtin_amdgcn_mfma_f32_32x32x16_bf16(
          __builtin_bit_cast(v8bf, f3), __builtin_bit_cast(v8bf, breg[k + 3]), a1, 0, 0, 0);
      f3 = np[192];
      a0 = __builtin_amdgcn_mfma_f32_32x32x16_bf16(
          __builtin_bit_cast(v8bf, f4), __builtin_bit_cast(v8bf, breg[k + 4]), a0, 0, 0, 0);
      f4 = np[256];
      a1 = __builtin_amdgcn_mfma_f32_32x32x16_bf16(
          __builtin_bit_cast(v8bf, f5), __builtin_bit_cast(v8bf, breg[k + 5]), a1, 0, 0, 0);
      f5 = np[320];
      a0 = __builtin_amdgcn_mfma_f32_32x32x16_bf16(
          __builtin_bit_cast(v8bf, f6), __builtin_bit_cast(v8bf, breg[k + 6]), a0, 0, 0, 0);
      f6 = np[384];
      a1 = __builtin_amdgcn_mfma_f32_32x32x16_bf16(
          __builtin_bit_cast(v8bf, f7), __builtin_bit_cast(v8bf, breg[k + 7]), a1, 0, 0, 0);
      f7 = np[448];
    }
    fp += 2048;

    // ---- fold this 32-group tile into running (M,E,S) ----
    // group offset within tile = j + 8*q + 4*lhi (reg = q*4+j);
    // subject = 2*(h*16+gt) + (q>>1); label = offset & 15.
    float mloc = -3.0e38f;
    float u0 = 0.f, u1 = 0.f;
#pragma unroll
    for (int q = 0; q < 4; ++q){
      v4f sc = *(const v4f*)&sscale[(h * 16 + gt) * 32 + q * 8 + lhi * 4];
#pragma unroll
      for (int j = 0; j < 4; ++j){
        float t = (a0[q * 4 + j] + a1[q * 4 + j]) * sc[j];
        mloc = fmaxf(mloc, t);
        if (q < 2) u0 = (q == qm1     && j == jm) ? t : u0;
        else       u1 = (q == qm1 + 2 && j == jm) ? t : u1;
      }
    }
    float Mn = fmaxf(M, mloc);
    int sub0 = 2 * (h * 16 + gt);
    float m0 = (lhi_ok && (sub0     != rsub)) ? 1.0f : 0.0f;
    float m1 = (lhi_ok && (sub0 + 1 != rsub)) ? 1.0f : 0.0f;
    E = E * exp2f(M - Mn) + m0 * exp2f(u0 - Mn) + m1 * exp2f(u1 - Mn);
    S += m0 * u0 + m1 * u1;
    M = Mn;
  }

  // lane^32 holds the same cf row's other group-offset half
  {
    float mo = __shfl_xor(M, 32), eo = __shfl_xor(E, 32), so = __shfl_xor(S, 32);
    float mn = fmaxf(M, mo);
    E = E * exp2f(M - mn) + eo * exp2f(mo - mn);
    S += so; M = mn;
  }
  if (lhi == 0){
    redM[w * 32 + l31] = M; redE[w * 32 + l31] = E; redS[w * 32 + l31] = S;
  }
  __syncthreads();
  if (tid < 64){
    float m0 = redM[tid], e0 = redE[tid], s0 = redS[tid];                   // h = 0
    float m1 = redM[tid + 64], e1 = redE[tid + 64], s1 = redS[tid + 64];    // h = 1
    float mn = fmaxf(m0, m1);
    float Ee = e0 * exp2f(m0 - mn) + e1 * exp2f(m1 - mn);
    float Ss = s0 + s1;
    float loss = logf(961.0f + Ee) + LN2 * mn - LN2 * (Ss * (1.0f / 63.0f));
    float ws = wredSum(loss);
    if (tid == 0) atomicAdd(out, ws * (1.0f / (float)ROWS));
  }
}

extern "C" void kernel_launch(void* const* d_in, const int* in_sizes, int n_in,
                              void* d_out, int out_size, void* d_ws, size_t ws_size,
                              hipStream_t stream){
  const float* X   = (const float*)d_in[0];
  const int* subj  = (const int*)d_in[1];
  const int* lab   = (const int*)d_in[2];
  char* ws = (char*)d_ws;

  int*    base_cnt = (int*)(ws + 0);          // 4 KB
  float*  msq      = (float*)(ws + 4096);     // 4 KB
  int*    offs     = (int*)(ws + 8192);       // 4 KB
  int*    gid_arr  = (int*)(ws + 12288);      // 64 KB
  int*    row_list = (int*)(ws + 77824);      // 64 KB
  float*  scale2   = (float*)(ws + 143360);   // 4 KB
  float*  cent_f   = (float*)(ws + 147456);   // 2 MB  (ends 2244608)
  __bf16* centP    = (__bf16*)(ws + 2244608); // 1 MB + 8 KB pad (ends 3301376)
  __bf16* cfb      = (__bf16*)(ws + 3301376); // 32 MB

  hipMemsetAsync(ws, 0, 8192, stream);        // base_cnt, msq
  hipMemsetAsync(d_out, 0, sizeof(float), stream);

  kA <<<1, 1024, 0, stream>>>(subj, lab, base_cnt, offs, gid_arr, row_list);
  kB <<<NGRP, 128, 0, stream>>>(X, base_cnt, offs, row_list, cent_f, centP);
  kC <<<8192, 256, 0, stream>>>(X, subj, lab, cent_f, msq, cfb);
  kD <<<1, 1024, 0, stream>>>(base_cnt, msq, scale2);
  kE <<<512, 256, 0, stream>>>(cfb, (const u32x4*)centP, scale2, gid_arr, (float*)d_out);
}